// Round 9
// baseline (1360.016 us; speedup 1.0000x reference)
//
#include <hip/hip_runtime.h>

typedef short short8 __attribute__((ext_vector_type(8)));
typedef float f32x4 __attribute__((ext_vector_type(4)));

#define XP_BYTES (16ull * 130 * 130 * 128 * 2)

static __device__ __forceinline__ unsigned short f2bf(float f) {
  unsigned u = __float_as_uint(f);
  u += 0x7FFFu + ((u >> 16) & 1u);
  return (unsigned short)(u >> 16);
}

static __device__ __forceinline__ void gload16(const void* g, void* l) {
  __builtin_amdgcn_global_load_lds(
      (const __attribute__((address_space(1))) void*)g,
      (__attribute__((address_space(3))) void*)l, 16, 0, 0);
}

// ---------------- weight rotation: (O*R,I,3,3) fp32 -> W2[n'=o*8+r][tap*128+ic] bf16
static __device__ __forceinline__ float wtap(const float* f, int yi, int xi) {
  bool valid = (yi >= 0) & (yi < 3) & (xi >= 0) & (xi < 3);
  int yc = min(max(yi, 0), 2), xc = min(max(xi, 0), 2);
  return valid ? f[yc * 3 + xc] : 0.f;
}

__global__ __launch_bounds__(256) void wprep_kernel(
    const float* __restrict__ w, const float* __restrict__ rot_alpha,
    unsigned short* __restrict__ w2) {
  int gid = blockIdx.x * 256 + threadIdx.x;  // 131072 = 1024 * 128
  int ic = gid & 127;
  int nr = gid >> 7;  // n' = o*8 + r
  int r = nr & 7;
  const float* wf = w + (size_t)nr * (128 * 9) + (size_t)ic * 9;
  float f[9];
#pragma unroll
  for (int q = 0; q < 9; ++q) f[q] = wf[q];
  float ang = rot_alpha[r] * 0.78539816339744830962f * (float)r;
  float sth, cth;
  sincosf(ang, &sth, &cth);
#pragma unroll
  for (int j = 0; j < 3; ++j) {
#pragma unroll
    for (int i = 0; i < 3; ++i) {
      float gy = (float)(j - 1), gx = (float)(i - 1);
      float xs = cth * gx - sth * gy;
      float ys = sth * gx + cth * gy;
      float ix = xs + 1.0f, iy = ys + 1.0f;
      float x0f = floorf(ix), y0f = floorf(iy);
      int x0 = (int)x0f, y0 = (int)y0f;
      float wx = ix - x0f, wy = iy - y0f;
      float acc = wtap(f, y0, x0) * (1.f - wy) * (1.f - wx)
                + wtap(f, y0, x0 + 1) * (1.f - wy) * wx
                + wtap(f, y0 + 1, x0) * wy * (1.f - wx)
                + wtap(f, y0 + 1, x0 + 1) * wy * wx;
      w2[(size_t)nr * 1152 + (size_t)(j * 3 + i) * 128 + ic] = f2bf(acc);
    }
  }
}

// ---------------- x: NCHW fp32 -> padded NHWC bf16 xp[16][130][130][128]
__global__ __launch_bounds__(256) void xprep_kernel(
    const float* __restrict__ x, unsigned short* __restrict__ xp) {
  const int yy = blockIdx.x;  // 0..129
  const int b = blockIdx.y;   // 0..15
  const int t = threadIdx.x;
  const size_t rowbase = ((size_t)b * 130 + yy) * (130 * 128);
  if (yy == 0 || yy == 129) {
    uint4 z = {0u, 0u, 0u, 0u};
    for (int i = t; i < 2080; i += 256)
      ((uint4*)(xp + rowbase))[i] = z;
    return;
  }
  const int y = yy - 1;
  __shared__ float lt[32][129];
  if (t < 32) {
    uint4 z = {0u, 0u, 0u, 0u};
    int xx = (t < 16) ? 0 : 129;
    int cc = (t & 15) * 8;
    *(uint4*)(xp + rowbase + (size_t)xx * 128 + cc) = z;
  }
  for (int c0 = 0; c0 < 128; c0 += 32) {
#pragma unroll
    for (int i = 0; i < 16; ++i) {
      int idx = i * 256 + t;
      int c = idx >> 7, wq = idx & 127;
      lt[c][wq] = x[(((size_t)b * 128 + c0 + c) * 128 + y) * 128 + wq];
    }
    __syncthreads();
#pragma unroll
    for (int i = 0; i < 2; ++i) {
      int u = i * 256 + t;
      int xx = u >> 2, cp = (u & 3) * 8;
      unsigned short v[8];
#pragma unroll
      for (int q = 0; q < 8; ++q) v[q] = f2bf(lt[cp + q][xx]);
      *(uint4*)(xp + rowbase + (size_t)(xx + 1) * 128 + c0 + cp) = *(uint4*)v;
    }
    __syncthreads();
  }
}

// ---------------- implicit-GEMM conv, 128x128 tile, BK=64, 4 waves, 2 blocks/CU.
// A staged via global_load_lds into 32 KiB LDS (swizzled, verified path).
// B read DIRECTLY global->register (L2-resident 2.25 MiB), double-buffered
// b0/b1, killing all B ds_reads + B staging writes (LDS unit was the
// saturated resource at ~74% busy). One barrier + one deep vmcnt(0)/K-tile.
__global__ __launch_bounds__(256, 2) void conv_kernel(
    const unsigned short* __restrict__ xp,
    const unsigned short* __restrict__ w2,
    float* __restrict__ out) {
  __shared__ unsigned short lds[16384];  // 32 KiB: [2buf][2kk][2half][64row][32k]

  const int tid = threadIdx.x;
  const int lane = tid & 63;
  const int wv = tid >> 6;  // 0..3
  const int wr = wv >> 1;   // M half (64 rows)
  const int wc = wv & 1;    // N half (64 n')

  const int bid = blockIdx.x;
  const int wg = (bid & 7) * 2048 + (bid >> 3);  // XCD swizzle (16384 % 8 == 0)
  const int mblk = wg >> 3;  // 0..2047
  const int nblk = wg & 7;   // 0..7
  const int b = mblk >> 7;
  const int y = mblk & 127;

  // A staging decode: thread t covers row r0 (0..63), lds slot s0 (16B, 4/row)
  const int r0 = tid >> 2;
  const int s0 = tid & 3;
  const int g0 = s0 ^ ((r0 >> 1) & 3);  // inverse swizzle on global source

  const unsigned short* xpt =
      xp + (size_t)(b * 130 + y) * 130 * 128 + r0 * 128 + g0 * 8;

  const int l15 = lane & 15;
  const int lhi = lane >> 4;
  const int sa = (lhi ^ ((l15 >> 1) & 3)) * 8;  // read-side swizzled slot
  const int aRd = wr * 2048 + l15 * 32 + sa;    // + buf*8192 + kk*4096

  // B global base: row = nblk*128 + wc*64 + nf*16 + l15 ; 16B chunk lhi
  const unsigned short* wb =
      w2 + (size_t)(nblk * 128 + wc * 64 + l15) * 1152 + lhi * 8;

  f32x4 acc[4][4];
#pragma unroll
  for (int mf = 0; mf < 4; ++mf)
#pragma unroll
    for (int nf = 0; nf < 4; ++nf) acc[mf][nf] = (f32x4){0.f, 0.f, 0.f, 0.f};

  // stage A K-tile T into BUF: 4 gloads (kk x half), each 64row x 32k
#define STAGE_T(BUF, T)                                                       \
  {                                                                           \
    const int tp_ = (T) >> 1, c_ = (T) & 1;                                   \
    const int dy_ = tp_ / 3, dx_ = tp_ - dy_ * 3;                             \
    _Pragma("unroll") for (int kk_ = 0; kk_ < 2; ++kk_)                       \
        _Pragma("unroll") for (int hf_ = 0; hf_ < 2; ++hf_)                   \
            gload16(xpt + ((size_t)dy_ * 130 + hf_ * 64 + dx_) * 128 +        \
                        c_ * 64 + kk_ * 32,                                   \
                    lds + (BUF) * 8192 + kk_ * 4096 + hf_ * 2048 + wv * 512); \
  }

  // load B K-tile T into DST[8] (kk*4+nf), one dwordx4 per lane per frag
#define B_LOAD(DST, T)                                                        \
  {                                                                           \
    const int tp_ = (T) >> 1, c_ = (T) & 1;                                   \
    const unsigned short* wb_ = wb + tp_ * 128 + c_ * 64;                     \
    _Pragma("unroll") for (int kk_ = 0; kk_ < 2; ++kk_)                       \
        _Pragma("unroll") for (int nf_ = 0; nf_ < 4; ++nf_)                   \
            DST[kk_ * 4 + nf_] =                                              \
                *(const short8*)(wb_ + nf_ * 18432 + kk_ * 32);               \
  }

#define COMPUTE(BUF, BREG)                                                    \
  {                                                                           \
    const unsigned short* pA_ = lds + (BUF) * 8192 + aRd;                     \
    short8 af[8];                                                             \
    _Pragma("unroll") for (int q = 0; q < 4; ++q)                             \
        af[q] = *(const short8*)(pA_ + q * 512);                              \
    _Pragma("unroll") for (int q = 0; q < 4; ++q)                             \
        af[4 + q] = *(const short8*)(pA_ + 4096 + q * 512);                   \
    __builtin_amdgcn_s_setprio(1);                                            \
    _Pragma("unroll") for (int q = 0; q < 4; ++q)                             \
        _Pragma("unroll") for (int n = 0; n < 4; ++n)                         \
            acc[q][n] = __builtin_amdgcn_mfma_f32_16x16x32_bf16(              \
                af[q], BREG[n], acc[q][n], 0, 0, 0);                          \
    _Pragma("unroll") for (int q = 0; q < 4; ++q)                             \
        _Pragma("unroll") for (int n = 0; n < 4; ++n)                         \
            acc[q][n] = __builtin_amdgcn_mfma_f32_16x16x32_bf16(              \
                af[4 + q], BREG[4 + n], acc[q][n], 0, 0, 0);                  \
    __builtin_amdgcn_s_setprio(0);                                            \
  }

#define VMW0 asm volatile("s_waitcnt vmcnt(0)" ::: "memory")
#define SCH0 __builtin_amdgcn_sched_barrier(0)

  short8 b0[8], b1[8];

  // ---- prologue: batch(0) = B(0)->b0 + A(0)->buf0
  B_LOAD(b0, 0);
  STAGE_T(0, 0);
  VMW0;
  __builtin_amdgcn_s_barrier();

#pragma unroll 1
  for (int i = 0; i < 9; ++i) {
    const int te = 2 * i, to = te + 1;
    // ---- tile te (buf0, b0); issue batch(to) -> buf1, b1
    B_LOAD(b1, to);
    STAGE_T(1, to);
    SCH0;
    COMPUTE(0, b0);
    VMW0;  // batch(to) landed (issued one compute-phase ago)
    __builtin_amdgcn_s_barrier();
    // ---- tile to (buf1, b1); issue batch(te+2) -> buf0, b0
    if (i < 8) {
      B_LOAD(b0, te + 2);
      STAGE_T(0, te + 2);
    }
    SCH0;
    COMPUTE(1, b1);
    VMW0;
    __builtin_amdgcn_s_barrier();
  }

#undef VMW0
#undef SCH0
#undef COMPUTE
#undef B_LOAD
#undef STAGE_T

  // ---- epilogue: max over 8 rotations (8 adjacent n' cols), coalesced store
  float* lE = (float*)lds;  // [128 pix][17] fp32
#pragma unroll
  for (int mf = 0; mf < 4; ++mf)
#pragma unroll
    for (int nf = 0; nf < 4; ++nf)
#pragma unroll
      for (int j = 0; j < 4; ++j) {
        float v = acc[mf][nf][j];
        v = fmaxf(v, __shfl_xor(v, 1, 64));
        v = fmaxf(v, __shfl_xor(v, 2, 64));
        v = fmaxf(v, __shfl_xor(v, 4, 64));
        if ((lane & 7) == 0) {
          int pix = wr * 64 + mf * 16 + lhi * 4 + j;
          int ol = wc * 8 + nf * 2 + ((lane >> 3) & 1);
          lE[pix * 17 + ol] = v;
        }
      }
  __syncthreads();
  const size_t obase = ((size_t)(b * 128 + nblk * 16) * 128 + y) * 128;
#pragma unroll
  for (int i = 0; i < 8; ++i) {
    int idx = i * 256 + tid;
    int ol = idx >> 7;   // 0..15
    int xx = idx & 127;
    out[obase + (size_t)ol * 16384 + xx] = lE[xx * 17 + ol];
  }
}

extern "C" void kernel_launch(void* const* d_in, const int* in_sizes, int n_in,
                              void* d_out, int out_size, void* d_ws, size_t ws_size,
                              hipStream_t stream) {
  const float* x = (const float*)d_in[0];
  const float* w = (const float*)d_in[1];
  const float* ra = (const float*)d_in[2];
  float* out = (float*)d_out;
  unsigned short* xp = (unsigned short*)d_ws;
  unsigned short* w2 = (unsigned short*)((char*)d_ws + XP_BYTES);

  hipLaunchKernelGGL(wprep_kernel, dim3(512), dim3(256), 0, stream, w, ra, w2);
  hipLaunchKernelGGL(xprep_kernel, dim3(130, 16), dim3(256), 0, stream, x, xp);
  hipLaunchKernelGGL(conv_kernel, dim3(16384), dim3(256), 0, stream, xp, w2, out);
}

// Round 10
// 724.108 us; speedup vs baseline: 1.8782x; 1.8782x over previous
//
#include <hip/hip_runtime.h>

typedef short short8 __attribute__((ext_vector_type(8)));
typedef float f32x4 __attribute__((ext_vector_type(4)));

#define XP_BYTES (16ull * 130 * 130 * 128 * 2)

static __device__ __forceinline__ unsigned short f2bf(float f) {
  unsigned u = __float_as_uint(f);
  u += 0x7FFFu + ((u >> 16) & 1u);
  return (unsigned short)(u >> 16);
}

static __device__ __forceinline__ void gload16(const void* g, void* l) {
  __builtin_amdgcn_global_load_lds(
      (const __attribute__((address_space(1))) void*)g,
      (__attribute__((address_space(3))) void*)l, 16, 0, 0);
}

// ---------------- weight rotation: (O*R,I,3,3) fp32 -> W2[n'=o*8+r][tap*128+ic] bf16
static __device__ __forceinline__ float wtap(const float* f, int yi, int xi) {
  bool valid = (yi >= 0) & (yi < 3) & (xi >= 0) & (xi < 3);
  int yc = min(max(yi, 0), 2), xc = min(max(xi, 0), 2);
  return valid ? f[yc * 3 + xc] : 0.f;
}

__global__ __launch_bounds__(256) void wprep_kernel(
    const float* __restrict__ w, const float* __restrict__ rot_alpha,
    unsigned short* __restrict__ w2) {
  int gid = blockIdx.x * 256 + threadIdx.x;  // 131072 = 1024 * 128
  int ic = gid & 127;
  int nr = gid >> 7;  // n' = o*8 + r
  int r = nr & 7;
  const float* wf = w + (size_t)nr * (128 * 9) + (size_t)ic * 9;
  float f[9];
#pragma unroll
  for (int q = 0; q < 9; ++q) f[q] = wf[q];
  float ang = rot_alpha[r] * 0.78539816339744830962f * (float)r;
  float sth, cth;
  sincosf(ang, &sth, &cth);
#pragma unroll
  for (int j = 0; j < 3; ++j) {
#pragma unroll
    for (int i = 0; i < 3; ++i) {
      float gy = (float)(j - 1), gx = (float)(i - 1);
      float xs = cth * gx - sth * gy;
      float ys = sth * gx + cth * gy;
      float ix = xs + 1.0f, iy = ys + 1.0f;
      float x0f = floorf(ix), y0f = floorf(iy);
      int x0 = (int)x0f, y0 = (int)y0f;
      float wx = ix - x0f, wy = iy - y0f;
      float acc = wtap(f, y0, x0) * (1.f - wy) * (1.f - wx)
                + wtap(f, y0, x0 + 1) * (1.f - wy) * wx
                + wtap(f, y0 + 1, x0) * wy * (1.f - wx)
                + wtap(f, y0 + 1, x0 + 1) * wy * wx;
      w2[(size_t)nr * 1152 + (size_t)(j * 3 + i) * 128 + ic] = f2bf(acc);
    }
  }
}

// ---------------- x: NCHW fp32 -> padded NHWC bf16 xp[16][130][130][128]
__global__ __launch_bounds__(256) void xprep_kernel(
    const float* __restrict__ x, unsigned short* __restrict__ xp) {
  const int yy = blockIdx.x;  // 0..129
  const int b = blockIdx.y;   // 0..15
  const int t = threadIdx.x;
  const size_t rowbase = ((size_t)b * 130 + yy) * (130 * 128);
  if (yy == 0 || yy == 129) {
    uint4 z = {0u, 0u, 0u, 0u};
    for (int i = t; i < 2080; i += 256)
      ((uint4*)(xp + rowbase))[i] = z;
    return;
  }
  const int y = yy - 1;
  __shared__ float lt[32][129];
  if (t < 32) {
    uint4 z = {0u, 0u, 0u, 0u};
    int xx = (t < 16) ? 0 : 129;
    int cc = (t & 15) * 8;
    *(uint4*)(xp + rowbase + (size_t)xx * 128 + cc) = z;
  }
  for (int c0 = 0; c0 < 128; c0 += 32) {
#pragma unroll
    for (int i = 0; i < 16; ++i) {
      int idx = i * 256 + t;
      int c = idx >> 7, wq = idx & 127;
      lt[c][wq] = x[(((size_t)b * 128 + c0 + c) * 128 + y) * 128 + wq];
    }
    __syncthreads();
#pragma unroll
    for (int i = 0; i < 2; ++i) {
      int u = i * 256 + t;
      int xx = u >> 2, cp = (u & 3) * 8;
      unsigned short v[8];
#pragma unroll
      for (int q = 0; q < 8; ++q) v[q] = f2bf(lt[cp + q][xx]);
      *(uint4*)(xp + rowbase + (size_t)(xx + 1) * 128 + c0 + cp) = *(uint4*)v;
    }
    __syncthreads();
  }
}

// ---------------- implicit-GEMM conv, 128x128 tile, BK=32, 4 waves, 48 KiB LDS,
// TRIPLE-buffered -> 3 independent blocks per CU (12 waves/CU) for TLP latency
// hiding: when one block's waves stall on lgkm, another's feed the MFMA pipe.
// Per K-tile: stage t+2 into buf (t+2)%3 (4 gloads); 8 ds_read_b128; 16 MFMA;
// vmcnt(4) forces t+1 landed; barrier. Loop unrolled x3 for static buf indices.
// LDS: A[3 buf][128 row][32 k] @ 0 + B[3 buf][128 n'][32 k] @ 12288 shorts.
__global__ __launch_bounds__(256, 3) void conv_kernel(
    const unsigned short* __restrict__ xp,
    const unsigned short* __restrict__ w2,
    float* __restrict__ out) {
  __shared__ unsigned short lds[24576];  // 48 KiB

  const int tid = threadIdx.x;
  const int lane = tid & 63;
  const int wv = tid >> 6;  // 0..3
  const int wr = wv >> 1;   // M half (64 rows)
  const int wc = wv & 1;    // N half (64 n')

  const int bid = blockIdx.x;
  const int wg = (bid & 7) * 2048 + (bid >> 3);  // XCD swizzle (16384 % 8 == 0)
  const int mblk = wg >> 3;  // 0..2047
  const int nblk = wg & 7;   // 0..7
  const int b = mblk >> 7;
  const int y = mblk & 127;

  // staging decode: thread t covers row r0 (0..63), lds slot s0 (16B, 4/row)
  const int r0 = tid >> 2;
  const int s0 = tid & 3;
  const int g0 = s0 ^ ((r0 >> 1) & 3);  // inverse swizzle on global source

  const unsigned short* xpt =
      xp + (size_t)(b * 130 + y) * 130 * 128 + r0 * 128 + g0 * 8;
  const unsigned short* wpt =
      w2 + (size_t)nblk * 128 * 1152 + (size_t)r0 * 1152 + g0 * 8;

  const int l15 = lane & 15;
  const int lhi = lane >> 4;
  const int sa = (lhi ^ ((l15 >> 1) & 3)) * 8;  // read-side swizzled slot
  const int aRd = wr * 2048 + l15 * 32 + sa;            // + p*4096
  const int bRd = 12288 + wc * 2048 + l15 * 32 + sa;    // + p*4096

  f32x4 acc[4][4];
#pragma unroll
  for (int mf = 0; mf < 4; ++mf)
#pragma unroll
    for (int nf = 0; nf < 4; ++nf) acc[mf][nf] = (f32x4){0.f, 0.f, 0.f, 0.f};

  // stage K-tile T (tap=T>>2, chq=T&3) into buf P: 4 gloads (A hf0/1, B hf0/1)
#define STAGE_T(P, T)                                                         \
  {                                                                           \
    const int tp_ = (T) >> 2, cq_ = (T) & 3;                                  \
    const int dy_ = tp_ / 3, dx_ = tp_ - dy_ * 3;                             \
    _Pragma("unroll") for (int hf_ = 0; hf_ < 2; ++hf_) {                     \
      gload16(xpt + ((size_t)dy_ * 130 + hf_ * 64 + dx_) * 128 + cq_ * 32,    \
              lds + (P) * 4096 + hf_ * 2048 + wv * 512);                      \
      gload16(wpt + (size_t)hf_ * 64 * 1152 + tp_ * 128 + cq_ * 32,           \
              lds + 12288 + (P) * 4096 + hf_ * 2048 + wv * 512);              \
    }                                                                         \
  }

#define VMW4 asm volatile("s_waitcnt vmcnt(4)" ::: "memory")
#define VMW0 asm volatile("s_waitcnt vmcnt(0)" ::: "memory")
#define SCH0 __builtin_amdgcn_sched_barrier(0)

  // tile T from buf P; stage T+2 into PN2
#define BODY(P, PN2, T)                                                       \
  {                                                                           \
    if ((T) + 2 < 36) STAGE_T(PN2, (T) + 2);                                  \
    const unsigned short* pA_ = lds + (P) * 4096 + aRd;                       \
    const unsigned short* pB_ = lds + (P) * 4096 + bRd;                       \
    short8 af[4], bf[4];                                                      \
    _Pragma("unroll") for (int q = 0; q < 4; ++q)                             \
        af[q] = *(const short8*)(pA_ + q * 512);                              \
    _Pragma("unroll") for (int n = 0; n < 4; ++n)                             \
        bf[n] = *(const short8*)(pB_ + n * 512);                              \
    __builtin_amdgcn_s_setprio(1);                                            \
    _Pragma("unroll") for (int q = 0; q < 4; ++q)                             \
        _Pragma("unroll") for (int n = 0; n < 4; ++n)                         \
            acc[q][n] = __builtin_amdgcn_mfma_f32_16x16x32_bf16(              \
                af[q], bf[n], acc[q][n], 0, 0, 0);                            \
    __builtin_amdgcn_s_setprio(0);                                            \
    SCH0;                                                                     \
    if ((T) < 34) { VMW4; } else { VMW0; }                                    \
    __builtin_amdgcn_s_barrier();                                             \
  }

  // ---- prologue: stage t0 -> buf0, t1 -> buf1; force t0; barrier
  STAGE_T(0, 0);
  STAGE_T(1, 1);
  VMW4;
  SCH0;
  __builtin_amdgcn_s_barrier();

#pragma unroll 1
  for (int j = 0; j < 12; ++j) {
    const int t0 = j * 3;
    BODY(0, 2, t0);
    BODY(1, 0, t0 + 1);
    BODY(2, 1, t0 + 2);
  }

#undef BODY
#undef STAGE_T
#undef VMW4
#undef VMW0
#undef SCH0

  // ---- epilogue: max over 8 rotations (8 adjacent n' cols), coalesced store
  float* lE = (float*)lds;  // [128 pix][17] fp32
#pragma unroll
  for (int mf = 0; mf < 4; ++mf)
#pragma unroll
    for (int nf = 0; nf < 4; ++nf)
#pragma unroll
      for (int j = 0; j < 4; ++j) {
        float v = acc[mf][nf][j];
        v = fmaxf(v, __shfl_xor(v, 1, 64));
        v = fmaxf(v, __shfl_xor(v, 2, 64));
        v = fmaxf(v, __shfl_xor(v, 4, 64));
        if ((lane & 7) == 0) {
          int pix = wr * 64 + mf * 16 + lhi * 4 + j;
          int ol = wc * 8 + nf * 2 + ((lane >> 3) & 1);
          lE[pix * 17 + ol] = v;
        }
      }
  __syncthreads();
  const size_t obase = ((size_t)(b * 128 + nblk * 16) * 128 + y) * 128;
#pragma unroll
  for (int i = 0; i < 8; ++i) {
    int idx = i * 256 + tid;
    int ol = idx >> 7;   // 0..15
    int xx = idx & 127;
    out[obase + (size_t)ol * 16384 + xx] = lE[xx * 17 + ol];
  }
}

extern "C" void kernel_launch(void* const* d_in, const int* in_sizes, int n_in,
                              void* d_out, int out_size, void* d_ws, size_t ws_size,
                              hipStream_t stream) {
  const float* x = (const float*)d_in[0];
  const float* w = (const float*)d_in[1];
  const float* ra = (const float*)d_in[2];
  float* out = (float*)d_out;
  unsigned short* xp = (unsigned short*)d_ws;
  unsigned short* w2 = (unsigned short*)((char*)d_ws + XP_BYTES);

  hipLaunchKernelGGL(wprep_kernel, dim3(512), dim3(256), 0, stream, w, ra, w2);
  hipLaunchKernelGGL(xprep_kernel, dim3(130, 16), dim3(256), 0, stream, x, xp);
  hipLaunchKernelGGL(conv_kernel, dim3(16384), dim3(256), 0, stream, xp, w2, out);
}